// Round 4
// baseline (124.751 us; speedup 1.0000x reference)
//
#include <hip/hip_runtime.h>
#include <hip/hip_bf16.h>

// out[b,i] = sum_{j<=i} x[b,j] * kernel[i-j]   (causal Toeplitz matmul)
// M=2048, N=K=4096. f32 in/out, bf16 MFMA compute.
//
// R9: A direct from L2, no A LDS. R7/R8 made each XCD's two A m-panels
// L2-resident (2 MB/XCD), so LDS-staging A is pure overhead: it cost 64
// ds_read_b128 + 32 KB global->LDS + a vmcnt(0)+barrier convoy EVERY step
// (~3.0K cyc/block-step vs 516 cyc matrix). prep now emits xb in a
// fragment-tiled layout (xb2[((rg*128+kb)*64+lane)*8], rg=16-row group,
// kb=32-elem K block) so an MFMA A-fragment load is ONE contiguous 1KB
// global_load_dwordx4 per wave. Main loop: af from global (compiler-scheduled
// vmcnt), b from LDS (krev shifted-copy trick unchanged), barrier only every
// 2 steps at B-chunk boundaries. LDS 80->36 KB. SGB/setprio dropped (R8
// showed ~neutral, consistent with T19/T5 evidence).

typedef unsigned short u16;
typedef __attribute__((ext_vector_type(8))) short  bf16x8;
typedef __attribute__((ext_vector_type(8))) unsigned short u16x8;
typedef __attribute__((ext_vector_type(4))) float  f32x4;

#define KDIM 4096
#define NDIM 4096
#define MDIM 2048
#define KREV_STRIDE 4608                    // elems per shifted copy
#define KREV_BYTES  (8 * KREV_STRIDE * 2)   // 73728
#define BSTRIDE 456                         // LDS B copy stride (elems); reads need [8,399)
#define BBUF    (8 * BSTRIDE)               // 3648 elems per B buffer

#define MFMA_BF16 __builtin_amdgcn_mfma_f32_16x16x32_bf16

static __device__ inline u16 f2bf(float f) {
  unsigned u = __builtin_bit_cast(unsigned, f);
  unsigned r = u + 0x7FFFu + ((u >> 16) & 1u);
  return (u16)(r >> 16);
}

static __device__ inline void async_copy16(const void* g, void* l) {
  __builtin_amdgcn_global_load_lds((const __attribute__((address_space(1))) void*)g,
                                   (__attribute__((address_space(3))) void*)l,
                                   16, 0, 0);
}

// Fused prep: blocks [0, conv_blocks) convert x->bf16 into the fragment-tiled
// layout; last 18 blocks build 8 shifted krev copies.
// Tiled layout: elem index = (rg*128 + kb)*512 + l*8 + e, where the 8 elems e
// are x[row = rg*16 + (l&15)][k = kb*32 + (l>>4)*8 + e]. One wave's fragment
// load (fixed rg,kb; l=lane) is 1KB contiguous.
__global__ __launch_bounds__(256) void prep(const float* __restrict__ x,
                                            const float* __restrict__ kern,
                                            u16* __restrict__ xb,
                                            u16* __restrict__ krevs,
                                            int conv_blocks) {
  int kblk = (int)blockIdx.x - conv_blocks;
  if (kblk >= 0) {
    int u = kblk * 256 + threadIdx.x;
    for (int a = 0; a < 8; ++a) {
      int t = u + a - 8;
      u16 v = 0;
      if (t >= 0 && t <= 4095) v = f2bf(kern[4095 - t]);
      krevs[a * KREV_STRIDE + u] = v;
    }
  } else {
    unsigned tg  = blockIdx.x * 256 + threadIdx.x;   // 0..2048*4096/8-1
    unsigned l   = tg & 63;
    unsigned kb  = (tg >> 6) & 127;
    unsigned rg  = tg >> 13;                         // 0..127
    unsigned row = rg * 16 + (l & 15);
    unsigned k   = kb * 32 + (l >> 4) * 8;
    const f32x4* p = (const f32x4*)(x + (size_t)row * KDIM + k);
    f32x4 v0 = p[0], v1 = p[1];
    u16x8 r;
    r[0] = f2bf(v0[0]); r[1] = f2bf(v0[1]); r[2] = f2bf(v0[2]); r[3] = f2bf(v0[3]);
    r[4] = f2bf(v1[0]); r[5] = f2bf(v1[1]); r[6] = f2bf(v1[2]); r[7] = f2bf(v1[3]);
    *(u16x8*)(xb + (size_t)tg * 8) = r;              // coalesced 1KB/wave
  }
}

template <bool CONV>
__global__ __launch_bounds__(512, 4) void toeplitz_gemm(const void* __restrict__ Av,
                                                        const u16* __restrict__ krevs,
                                                        float* __restrict__ out) {
  // LDS: B only, [2 bufs][8*456] = 14592 B, overlaid by 36864 B epilogue buf.
  __shared__ __align__(16) char smem_raw[36864];
  u16*   B_all = (u16*)smem_raw;
  f32x4* ep    = (f32x4*)smem_raw;            // epilogue overlay, 9 f32x4 per slot

  const int tid  = threadIdx.x;
  const int w    = tid >> 6;        // 0..7
  const int g    = w >> 2;          // K-group 0..1
  const int wl   = w & 3;           // wave-in-group
  const int lane = tid & 63;
  const int lane16 = lane & 15;
  const int quad   = lane >> 4;
  const int wm = wl >> 1;
  const int wn = wl & 1;

  // XCD-affine, balance-correct mapping (R8): XCD x_=b&7 owns m-panels
  // {x_,x_+8}; co-resident pair (b, b+256) shares one panel, ct sum = 31.
  const int b  = (int)blockIdx.x;
  const int x_ = b & 7;
  const int jj = b >> 3;                  // 0..63 within XCD
  const int q  = jj & 31;
  const int h  = jj >> 5;
  const int mt = x_ + 8 * (q & 1);        // m-panel 0..15
  const int ct = h ? (q >> 1) : 31 - (q >> 1);
  const int n0 = ct * 128;
  const int m0 = mt * 128;
  const int W  = 3968 - n0;               // B window base for chunk 0

  // B frag: elem j = krev_logical[s0 + k], s0 = 4095-n_g+quad*8; chunk c holds
  // krev_logical[W + c*256 + u + a - 8] at copy a elem u (u in [0,448)).
  int boff[4];
  for (int fn = 0; fn < 4; ++fn) {
    int n_g = n0 + wn * 64 + fn * 16 + lane16;
    int s0  = 4095 - n_g + quad * 8;
    int a   = s0 & 7;
    boff[fn] = a * BSTRIDE + (s0 - a + 8 - W);
  }

  f32x4 acc[4][4] = {};

  // A fragment bases. FAST: tiled elem idx = rg*65536 + kb*512 + lane*8,
  // rg = mt*8 + wm*4 + fm, kb = t*4 + g*2 + kk  -> per-t stride 2048 elems,
  // kk stride 512 elems (1KB imm). CONV: row-major f32 source.
  const u16*   xb2 = (const u16*)Av;
  const float* xf  = (const float*)Av;
  const u16* pA[4];
  if constexpr (!CONV) {
    for (int fm = 0; fm < 4; ++fm)
      pA[fm] = xb2 + (size_t)(mt * 8 + wm * 4 + fm) * 65536 + g * 1024 + lane * 8;
  }
  const int rowb = m0 + wm * 64 + lane16;   // CONV source row base

  auto stageB = [&](int c) {               // 8 waves x 56 lanes: 448 elems/copy
    if (lane < 56)
      async_copy16(krevs + w * KREV_STRIDE + W + c * 256 + (lane << 3),
                   &B_all[(c & 1) * BBUF + w * BSTRIDE]);
  };

  // prologue: B chunk 0 resident before first compute
  stageB(0);
  asm volatile("s_waitcnt vmcnt(0) lgkmcnt(0)" ::: "memory");
  __builtin_amdgcn_s_barrier();
  asm volatile("" ::: "memory");

  const int cmax = ct >> 1;
  for (int t = 0; ; ++t) {
    // issue next B chunk at even steps (buffer freed by barrier at end of t-1)
    if (!(t & 1) && ((t >> 1) + 1) <= cmax) stageB((t >> 1) + 1);

    const u16* Bb  = B_all + ((t >> 1) & 1) * BBUF;
    const int  ksl = (t & 1) * 128 + g * 64;
#pragma unroll
    for (int kk = 0; kk < 2; ++kk) {
      bf16x8 af[4];
      if constexpr (!CONV) {
        const int eo = t * 2048 + kk * 512;
        for (int fm = 0; fm < 4; ++fm)
          af[fm] = *(const bf16x8*)(pA[fm] + eo);    // 1KB contiguous per wave
      } else {
        const int k0 = t * 128 + g * 64 + kk * 32 + quad * 8;
        for (int fm = 0; fm < 4; ++fm) {
          const f32x4* px = (const f32x4*)(xf + (size_t)(rowb + fm * 16) * KDIM + k0);
          f32x4 v0 = px[0], v1 = px[1];
          u16x8 r;
          r[0]=f2bf(v0[0]); r[1]=f2bf(v0[1]); r[2]=f2bf(v0[2]); r[3]=f2bf(v0[3]);
          r[4]=f2bf(v1[0]); r[5]=f2bf(v1[1]); r[6]=f2bf(v1[2]); r[7]=f2bf(v1[3]);
          af[fm] = __builtin_bit_cast(bf16x8, r);
        }
      }
      bf16x8 bfr[4];
      for (int fn = 0; fn < 4; ++fn)
        bfr[fn] = *(const bf16x8*)(&Bb[boff[fn] + ksl + kk * 32]);
      for (int fm = 0; fm < 4; ++fm)
        for (int fn = 0; fn < 4; ++fn)
          acc[fm][fn] = MFMA_BF16(af[fm], bfr[fn], acc[fm][fn], 0, 0, 0);
    }
    if (t == ct) break;
    if (t & 1) {   // B-chunk boundary: stage drained, buffers swap
      asm volatile("s_waitcnt vmcnt(0) lgkmcnt(0)" ::: "memory");
      __builtin_amdgcn_s_barrier();
      asm volatile("" ::: "memory");
    }
  }

  // combine: group1's partials -> group0 via LDS (2 rounds of 2 fm each)
  const int j = tid & 255;
  for (int r = 0; r < 2; ++r) {
    __syncthreads();                       // (r=0: also fences last compute reads)
    if (g == 1) {
      for (int fm2 = 0; fm2 < 2; ++fm2)
        for (int fn = 0; fn < 4; ++fn)
          ep[j * 9 + fm2 * 4 + fn] = acc[r * 2 + fm2][fn];
    }
    __syncthreads();
    if (g == 0) {
      for (int fm2 = 0; fm2 < 2; ++fm2)
        for (int fn = 0; fn < 4; ++fn)
          acc[r * 2 + fm2][fn] += ep[j * 9 + fm2 * 4 + fn];
    }
  }

  // epilogue (group 0 only): C/D layout col=lane&15, row=quad*4+r
  if (g == 0) {
    for (int fm = 0; fm < 4; ++fm) {
      int row_base = m0 + wm * 64 + fm * 16 + quad * 4;
      for (int fn = 0; fn < 4; ++fn) {
        int col = n0 + wn * 64 + fn * 16 + lane16;
        for (int r = 0; r < 4; ++r)
          out[(size_t)(row_base + r) * NDIM + col] = acc[fm][fn][r];
      }
    }
  }
}

extern "C" void kernel_launch(void* const* d_in, const int* in_sizes, int n_in,
                              void* d_out, int out_size, void* d_ws, size_t ws_size,
                              hipStream_t stream) {
  const float* x    = (const float*)d_in[0];
  const float* kern = (const float*)d_in[1];
  float* out = (float*)d_out;

  u16* krevs = (u16*)d_ws;
  u16* xb    = (u16*)((char*)d_ws + KREV_BYTES);
  const size_t need_fast = (size_t)KREV_BYTES + (size_t)MDIM * KDIM * 2;

  if (ws_size >= need_fast) {
    prep<<<4096 + 18, 256, 0, stream>>>(x, kern, xb, krevs, 4096);
    toeplitz_gemm<false><<<512, 512, 0, stream>>>(xb, krevs, out);
  } else {
    prep<<<18, 256, 0, stream>>>(x, kern, xb, krevs, 0);
    toeplitz_gemm<true><<<512, 512, 0, stream>>>(x, krevs, out);
  }
}